// Round 4
// baseline (321.107 us; speedup 1.0000x reference)
//
#include <hip/hip_runtime.h>
#include <cstdint>
#include <cstddef>

#define BB 32
#define NN 8400
#define NCC 80
#define MM 40
#define RM 16
#define TOPKK 10
#define CAP 2048      // max positives per (b,m); measured ~450 worst case
#define SLOTP 42      // fp16 slot stride; 21 words, gcd(21,32)=1 -> conflict-free gather

// ---------- helpers ----------
__device__ __forceinline__ void anchor_xy(int n, float& ax, float& ay) {
    int s, x, y;
    if (n < 6400)      { s = 8;  y = n / 80;            x = n - y * 80; }
    else if (n < 8000) { int i = n - 6400; s = 16; y = i / 40; x = i - y * 40; }
    else               { int i = n - 8000; s = 32; y = i / 20; x = i - y * 20; }
    ax = ((float)x + 0.5f) * (float)s;
    ay = ((float)y + 0.5f) * (float)s;
}

// ---------- K_main: DFL + sigmoid/softplus tile + align + sparse push ----------
// grid: (ceil(N/128), B), 256 threads, target 8 blocks/CU (32 waves).
__global__ __launch_bounds__(256, 8) void k_main(const float* __restrict__ ps,
                                                 const float* __restrict__ pd,
                                                 const int*   __restrict__ gl,
                                                 const float* __restrict__ gb,
                                                 const float* __restrict__ w,
                                                 float* __restrict__ pbb,
                                                 float* __restrict__ maxm,
                                                 int*   __restrict__ cnts,
                                                 unsigned long long* __restrict__ lists,
                                                 float* __restrict__ accum,
                                                 int*   __restrict__ tgt) {
    __shared__ _Float16 sc[128 * SLOTP];  // sigmoid per (nloc, slot), fp16
    __shared__ float4 box[128];           // ltrb then pred box
    __shared__ float  gtb[MM * 4];
    __shared__ int    glab[MM];
    __shared__ int    slotm[MM];
    __shared__ int    cmap[NCC];
    __shared__ float  cm[256];
    __shared__ float  redf[4];
    const int b  = blockIdx.y;
    const int n0 = blockIdx.x * 128;
    const int t  = threadIdx.x;

    // fold the tgt init (was a 1MB memset node): this block owns [n0, n0+128)
    if (t < 128 && n0 + t < NN) tgt[(size_t)b * NN + n0 + t] = 0x7F7F7F7F;

    if (t < MM * 4)              gtb[t] = gb[b * MM * 4 + t];
    if (t >= 192 && t < 192+MM)  glab[t - 192] = gl[b * MM + (t - 192)];
    if (t >= 64 && t < 64+NCC)   cmap[t - 64] = 0x7FFFFFFF;
    __syncthreads();
    if (t < MM) atomicMin(&cmap[glab[t]], t);   // parallel label dedup
    __syncthreads();
    if (t < MM) slotm[t] = cmap[glab[t]];       // slot = representative m, in [0,MM)

    // ---- phase 0: DFL softmax-dot for this block's 128 anchors (512 sides) ----
    #pragma unroll
    for (int h = 0; h < 2; h++) {
        int f = t + h * 256;                    // (anchor,side) flat in [0,512)
        int a = f >> 2, side = f & 3;
        int nc = min(n0 + a, NN - 1);
        const float* p = pd + (((size_t)(b * NN + nc)) * 4 + side) * RM;
        float x[RM];
        #pragma unroll
        for (int i = 0; i < 4; i++) {
            float4 v = *(const float4*)(p + i * 4);
            x[i*4+0] = v.x; x[i*4+1] = v.y; x[i*4+2] = v.z; x[i*4+3] = v.w;
        }
        float mx = x[0];
        #pragma unroll
        for (int i = 1; i < RM; i++) mx = fmaxf(mx, x[i]);
        float s = 0.f, d = 0.f;
        #pragma unroll
        for (int i = 0; i < RM; i++) {
            float e = __builtin_amdgcn_exp2f((x[i] - mx) * 1.44269504f);
            s += e; d += e * w[i];
        }
        ((float*)box)[f] = d * __builtin_amdgcn_rcpf(s);
    }
    __syncthreads();
    if (t < 128) {
        int n = n0 + t;
        float ax, ay; anchor_xy(min(n, NN - 1), ax, ay);
        float4 v = box[t];
        float4 pb = make_float4(ax - v.x, ay - v.y, ax + v.z, ay + v.w);
        box[t] = pb;
        if (n < NN) *(float4*)(pbb + (size_t)(b * NN + n) * 4) = pb;
    }

    // ---- phase 1: 128x80 score tile; two 5-load batches (VGPR <= 64 target) ----
    float sp = 0.f;
    #pragma unroll
    for (int half = 0; half < 2; half++) {
        float4 vv[5];
        #pragma unroll
        for (int k = 0; k < 5; k++) {
            int f = t + (half * 5 + k) * 256;   // [0,2560)
            int row = f / 20, c4 = f - row * 20;
            int nc = min(n0 + row, NN - 1);
            vv[k] = *(const float4*)(ps + ((size_t)(b * NN + nc)) * NCC + c4 * 4);
        }
        #pragma unroll
        for (int k = 0; k < 5; k++) {
            int f = t + (half * 5 + k) * 256;
            int row = f / 20, c4 = f - row * 20;
            float vmask = (n0 + row < NN) ? 1.f : 0.f;
            float xs[4] = {vv[k].x, vv[k].y, vv[k].z, vv[k].w};
            #pragma unroll
            for (int j = 0; j < 4; j++) {
                float x = xs[j];
                float e = __builtin_amdgcn_exp2f(-1.44269504f * fabsf(x));
                float r = __builtin_amdgcn_rcpf(1.0f + e);
                sp += vmask * (fmaxf(x, 0.f) + 0.69314718f * __builtin_amdgcn_logf(1.0f + e));
                int sl = cmap[c4 * 4 + j];
                if (sl < MM) sc[row * SLOTP + sl] = (_Float16)((x >= 0.f) ? r : e * r);
            }
        }
    }
    __syncthreads();

    // ---- phase 2: align for 20 gts per thread-half; push positives; col max ----
    const int nloc = t & 127;
    const int n    = n0 + nloc;
    const int mb   = (t >> 7) * 20;
    const int lane = t & 63;
    const bool valid = (n < NN);
    float cmax = -INFINITY;
    float4 p4 = box[nloc];
    const float px1 = p4.x, py1 = p4.y, px2 = p4.z, py2 = p4.w;
    const float a1 = (px2 - px1) * (py2 - py1);
    #pragma unroll
    for (int j = 0; j < 20; j++) {
        int m = mb + j;
        float gx1 = gtb[m*4+0], gy1 = gtb[m*4+1], gx2 = gtb[m*4+2], gy2 = gtb[m*4+3];
        float a2 = (gx2 - gx1) * (gy2 - gy1);
        float iw = fmaxf(fminf(px2, gx2) - fmaxf(px1, gx1), 0.f);
        float ih = fmaxf(fminf(py2, gy2) - fmaxf(py1, gy1), 0.f);
        float inter = iw * ih;
        float iou = fmaxf(inter * __builtin_amdgcn_rcpf(a1 + a2 - inter + 1e-16f), 0.f);
        float al = 0.f;
        if (valid) {
            float sg = (float)sc[nloc * SLOTP + slotm[m]];
            float i2 = iou * iou;
            al = __builtin_amdgcn_sqrtf(sg) * (i2 * i2 * i2);
        }
        cmax = fmaxf(cmax, al);
        bool pos = valid && (al > 1e-9f);
        unsigned long long msk = __ballot(pos);
        if (msk) {
            int leader = __ffsll((long long)msk) - 1;
            int basev = 0;
            if (lane == leader) basev = atomicAdd(&cnts[b * MM + m], __popcll(msk));
            basev = __shfl(basev, leader);
            if (pos) {
                int ofs = __popcll(msk & ((1ull << lane) - 1ull));
                int idx = basev + ofs;
                if (idx < CAP)
                    lists[((size_t)(b * MM + m)) * CAP + idx] =
                        ((unsigned long long)__float_as_uint(al) << 32) | (unsigned)n;
            }
        }
    }
    cm[t] = cmax;
    __syncthreads();
    if (t < 128 && valid) maxm[(size_t)b * NN + n] = fmaxf(cm[t], cm[t + 128]);

    // softplus block reduction -> one atomic
    #pragma unroll
    for (int off = 32; off > 0; off >>= 1) sp += __shfl_down(sp, off);
    if ((t & 63) == 0) redf[t >> 6] = sp;
    __syncthreads();
    if (t == 0) atomicAdd(accum, redf[0] + redf[1] + redf[2] + redf[3]);
}

// ---------- K_topk: top-10 of compacted positives, LDS-only passes ----------
__global__ __launch_bounds__(64) void k_topk(const unsigned long long* __restrict__ lists,
                                             const int*   __restrict__ cnts,
                                             const float* __restrict__ maxm,
                                             int* __restrict__ tgt) {
    __shared__ unsigned long long keys[CAP];
    __shared__ unsigned long long sel[TOPKK];
    const int bm = blockIdx.x, b = bm / MM, m = bm % MM, t = threadIdx.x;
    int cnt = min(cnts[bm], CAP);
    int kk = min(TOPKK, cnt);
    for (int i = t; i < cnt; i += 64) {
        unsigned long long L = lists[(size_t)bm * CAP + i];
        keys[i] = (L & 0xFFFFFFFF00000000ull) | (0xFFFFFFFFull - (L & 0xFFFFFFFFull));
    }
    __syncthreads();
    for (int p = 0; p < kk; p++) {
        unsigned long long best = 0ull;
        for (int i = t; i < cnt; i += 64) best = keys[i] > best ? keys[i] : best;
        #pragma unroll
        for (int off = 32; off > 0; off >>= 1) {
            unsigned long long o = __shfl_xor(best, off);
            best = o > best ? o : best;
        }
        for (int i = t; i < cnt; i += 64) if (keys[i] == best) keys[i] = 0ull;
        if (t == 0) sel[p] = best;
        __syncthreads();
    }
    if (t < kk) {
        unsigned long long bb = sel[t];
        float v = __uint_as_float((unsigned)(bb >> 32));
        int n = (int)(0xFFFFFFFFull - (bb & 0xFFFFFFFFull));
        if (v == maxm[(size_t)b * NN + n]) atomicMin(&tgt[(size_t)b * NN + n], m);
    }
}

// ---------- K_fg: fg accumulation + fused finalize (last block writes out) ----
__global__ __launch_bounds__(256) void k_fg(const int*   __restrict__ tgt,
                                            const int*   __restrict__ gl,
                                            const float* __restrict__ gb,
                                            const float* __restrict__ ps,
                                            const float* __restrict__ pbb,
                                            const float* __restrict__ maxm,
                                            float* __restrict__ accum,
                                            float* __restrict__ out) {
    int i = blockIdx.x * 256 + threadIdx.x;   // i in [0, B*N)
    int t = threadIdx.x;
    float vdot = 0.f, vbox = 0.f, vfg = 0.f;
    int tg = tgt[i];
    if (tg < MM) {
        int b = i / NN;
        int lab = gl[b * MM + tg];
        float x = ps[(size_t)i * NCC + lab];
        float mm = maxm[i];
        float4 p = *(const float4*)(pbb + (size_t)i * 4);
        const float* g = gb + ((size_t)b * MM + tg) * 4;
        float a1 = (p.z - p.x) * (p.w - p.y);
        float a2 = (g[2] - g[0]) * (g[3] - g[1]);
        float iw = fmaxf(fminf(p.z, g[2]) - fmaxf(p.x, g[0]), 0.f);
        float ih = fmaxf(fminf(p.w, g[3]) - fmaxf(p.y, g[1]), 0.f);
        float inter = iw * ih;
        float iou = inter / (a1 + a2 - inter + 1e-16f);
        vdot = x * mm; vbox = 1.0f - iou; vfg = 1.0f;
    }
    #pragma unroll
    for (int off = 32; off > 0; off >>= 1) {
        vdot += __shfl_down(vdot, off);
        vbox += __shfl_down(vbox, off);
        vfg  += __shfl_down(vfg,  off);
    }
    __shared__ float r[3][4];
    if ((t & 63) == 0) { int wv = t >> 6; r[0][wv] = vdot; r[1][wv] = vbox; r[2][wv] = vfg; }
    __syncthreads();
    if (t < 3) {
        float s = r[t][0] + r[t][1] + r[t][2] + r[t][3];
        if (s != 0.f) atomicAdd(&accum[1 + t], s);
    }
    __syncthreads();                 // block's atomics complete before signaling
    __threadfence();
    if (t == 0) {
        int old = atomicAdd((int*)&accum[7], 1);
        if (old == (int)gridDim.x - 1) {   // last block finalizes
            float S0  = atomicAdd(&accum[0], 0.f);
            float dot = atomicAdd(&accum[1], 0.f);
            float box = atomicAdd(&accum[2], 0.f);
            float fg  = atomicAdd(&accum[3], 0.f);
            float ts  = fmaxf(fg, 1.0f);
            float cls = (S0 - dot) / ts;
            float lb  = (fg > 0.f) ? box / fg : 0.f;
            out[0] = cls + 1.5f * lb;
        }
    }
}

// ---------- launch ----------
extern "C" void kernel_launch(void* const* d_in, const int* in_sizes, int n_in,
                              void* d_out, int out_size, void* d_ws, size_t ws_size,
                              hipStream_t stream) {
    const float* ps = (const float*)d_in[0];   // pred_scores (B,N,NC)
    const float* pd = (const float*)d_in[1];   // pred_dist   (B,N,64)
    const int*   gl = (const int*)  d_in[2];   // gt_labels   (B,M,1)
    const float* gb = (const float*)d_in[3];   // gt_bboxes   (B,M,4)
    const float* w  = (const float*)d_in[4];   // dfl_weight  (16)

    char* ws = (char*)d_ws;
    constexpr size_t HDR_BYTES  = 8192;                                     // accum(32B)+done + cnts(5120B)
    constexpr size_t PBB_BYTES  = (size_t)BB * NN * 4 * sizeof(float);      // 4.30 MB
    constexpr size_t MAXM_BYTES = (size_t)BB * NN * sizeof(float);          // 1.08 MB
    constexpr size_t TGT_BYTES  = (size_t)BB * NN * sizeof(int);            // 1.08 MB

    float* accum = (float*)ws;                 // [0]=S0 [1]=dot [2]=box [3]=fg [7]=done
    int*   cnts  = (int*)(ws + 64);
    float* pbb   = (float*)(ws + HDR_BYTES);
    float* maxm  = (float*)(ws + HDR_BYTES + PBB_BYTES);
    int*   tgt   = (int*)  (ws + HDR_BYTES + PBB_BYTES + MAXM_BYTES);
    unsigned long long* lists =
        (unsigned long long*)(ws + HDR_BYTES + PBB_BYTES + MAXM_BYTES + TGT_BYTES);

    hipMemsetAsync(ws, 0, HDR_BYTES, stream);  // accum + done + cnts in one node

    dim3 g3((NN + 127) / 128, BB);
    k_main<<<g3, 256, 0, stream>>>(ps, pd, gl, gb, w, pbb, maxm, cnts, lists, accum, tgt);
    k_topk<<<BB * MM, 64, 0, stream>>>(lists, cnts, maxm, tgt);
    k_fg<<<BB * NN / 256, 256, 0, stream>>>(tgt, gl, gb, ps, pbb, maxm, accum, (float*)d_out);
}

// Round 5
// 276.704 us; speedup vs baseline: 1.1605x; 1.1605x over previous
//
#include <hip/hip_runtime.h>
#include <cstdint>
#include <cstddef>

#define BB 32
#define NN 8400
#define NCC 80
#define MM 40
#define RM 16
#define TOPKK 10
#define CAP 2048      // max positives per (b,m); est worst case ~500, 4x margin
#define SLOTP 42      // fp16 slot stride; 21 words, gcd(21,32)=1 -> conflict-free gather

// ---------- helpers ----------
__device__ __forceinline__ void anchor_xy(int n, float& ax, float& ay) {
    int s, x, y;
    if (n < 6400)      { s = 8;  y = n / 80;            x = n - y * 80; }
    else if (n < 8000) { int i = n - 6400; s = 16; y = i / 40; x = i - y * 40; }
    else               { int i = n - 8000; s = 32; y = i / 20; x = i - y * 20; }
    ax = ((float)x + 0.5f) * (float)s;
    ay = ((float)y + 0.5f) * (float)s;
}

// ---------- K_main: DFL + sigmoid/softplus tile + align + sparse push ----------
// grid: (ceil(N/128), B), 256 threads. NO min-wave launch bound: forcing 8/EU
// spilled to scratch (round 4: WRITE_SIZE 5MB->177MB, 2x regression).
__global__ __launch_bounds__(256) void k_main(const float* __restrict__ ps,
                                              const float* __restrict__ pd,
                                              const int*   __restrict__ gl,
                                              const float* __restrict__ gb,
                                              const float* __restrict__ w,
                                              float* __restrict__ pbb,
                                              float* __restrict__ maxm,
                                              int*   __restrict__ cnts,
                                              unsigned long long* __restrict__ lists,
                                              float* __restrict__ accum,
                                              int*   __restrict__ tgt) {
    __shared__ _Float16 sc[128 * SLOTP];  // sigmoid per (nloc, slot), fp16
    __shared__ float4 box[128];           // ltrb then pred box
    __shared__ float  gtb[MM * 4];
    __shared__ int    glab[MM];
    __shared__ int    slotm[MM];
    __shared__ int    cmap[NCC];
    __shared__ int    pc[MM][2];          // per-(m, wave-within-half) popcount
    __shared__ int    baseLoc[MM];        // reserved global base per m
    __shared__ float  cm[256];
    __shared__ float  redf[4];
    const int b  = blockIdx.y;
    const int n0 = blockIdx.x * 128;
    const int t  = threadIdx.x;

    // folded tgt init: this block owns [n0, n0+128)
    if (t < 128 && n0 + t < NN) tgt[(size_t)b * NN + n0 + t] = 0x7F7F7F7F;

    if (t < MM * 4)              gtb[t] = gb[b * MM * 4 + t];
    if (t >= 192 && t < 192+MM)  glab[t - 192] = gl[b * MM + (t - 192)];
    if (t >= 64 && t < 64+NCC)   cmap[t - 64] = 0x7FFFFFFF;
    __syncthreads();
    if (t < MM) atomicMin(&cmap[glab[t]], t);   // parallel label dedup
    __syncthreads();
    if (t < MM) slotm[t] = cmap[glab[t]];       // slot = representative m, in [0,MM)

    // ---- phase 0: DFL softmax-dot for this block's 128 anchors (512 sides) ----
    #pragma unroll
    for (int h = 0; h < 2; h++) {
        int f = t + h * 256;                    // (anchor,side) flat in [0,512)
        int a = f >> 2, side = f & 3;
        int nc = min(n0 + a, NN - 1);
        const float* p = pd + (((size_t)(b * NN + nc)) * 4 + side) * RM;
        float x[RM];
        #pragma unroll
        for (int i = 0; i < 4; i++) {
            float4 v = *(const float4*)(p + i * 4);
            x[i*4+0] = v.x; x[i*4+1] = v.y; x[i*4+2] = v.z; x[i*4+3] = v.w;
        }
        float mx = x[0];
        #pragma unroll
        for (int i = 1; i < RM; i++) mx = fmaxf(mx, x[i]);
        float s = 0.f, d = 0.f;
        #pragma unroll
        for (int i = 0; i < RM; i++) {
            float e = __builtin_amdgcn_exp2f((x[i] - mx) * 1.44269504f);
            s += e; d += e * w[i];
        }
        ((float*)box)[f] = d * __builtin_amdgcn_rcpf(s);
    }
    __syncthreads();
    if (t < 128) {
        int n = n0 + t;
        float ax, ay; anchor_xy(min(n, NN - 1), ax, ay);
        float4 v = box[t];
        float4 pb = make_float4(ax - v.x, ay - v.y, ax + v.z, ay + v.w);
        box[t] = pb;
        if (n < NN) *(float4*)(pbb + (size_t)(b * NN + n) * 4) = pb;
    }

    // ---- phase 1: 128x80 score tile; two 5-load batches for ILP ----
    float sp = 0.f;
    #pragma unroll
    for (int half = 0; half < 2; half++) {
        float4 vv[5];
        #pragma unroll
        for (int k = 0; k < 5; k++) {
            int f = t + (half * 5 + k) * 256;   // [0,2560)
            int row = f / 20, c4 = f - row * 20;
            int nc = min(n0 + row, NN - 1);
            vv[k] = *(const float4*)(ps + ((size_t)(b * NN + nc)) * NCC + c4 * 4);
        }
        #pragma unroll
        for (int k = 0; k < 5; k++) {
            int f = t + (half * 5 + k) * 256;
            int row = f / 20, c4 = f - row * 20;
            float vmask = (n0 + row < NN) ? 1.f : 0.f;
            float xs[4] = {vv[k].x, vv[k].y, vv[k].z, vv[k].w};
            #pragma unroll
            for (int j = 0; j < 4; j++) {
                float x = xs[j];
                float e = __builtin_amdgcn_exp2f(-1.44269504f * fabsf(x));
                float r = __builtin_amdgcn_rcpf(1.0f + e);
                sp += vmask * (fmaxf(x, 0.f) + 0.69314718f * __builtin_amdgcn_logf(1.0f + e));
                int sl = cmap[c4 * 4 + j];
                if (sl < MM) sc[row * SLOTP + sl] = (_Float16)((x >= 0.f) ? r : e * r);
            }
        }
    }
    __syncthreads();

    // ---- phase 2: align, two-pass sparse push (no atomic dependence in loop) --
    const int nloc = t & 127;
    const int n    = n0 + nloc;
    const int mb   = (t >> 7) * 20;
    const int lane = t & 63;
    const int wv1  = (t >> 6) & 1;            // wave index within the m-half
    const bool valid = (n < NN);
    float4 p4 = box[nloc];
    const float px1 = p4.x, py1 = p4.y, px2 = p4.z, py2 = p4.w;
    const float a1 = (px2 - px1) * (py2 - py1);

    // pass A: ballots + per-(m,wave) counts + column max (no global ops)
    float cmax = -INFINITY;
    #pragma unroll
    for (int j = 0; j < 20; j++) {
        int m = mb + j;
        float gx1 = gtb[m*4+0], gy1 = gtb[m*4+1], gx2 = gtb[m*4+2], gy2 = gtb[m*4+3];
        float a2 = (gx2 - gx1) * (gy2 - gy1);
        float iw = fmaxf(fminf(px2, gx2) - fmaxf(px1, gx1), 0.f);
        float ih = fmaxf(fminf(py2, gy2) - fmaxf(py1, gy1), 0.f);
        float inter = iw * ih;
        float iou = fmaxf(inter * __builtin_amdgcn_rcpf(a1 + a2 - inter + 1e-16f), 0.f);
        float al = 0.f;
        if (valid) {
            float sg = (float)sc[nloc * SLOTP + slotm[m]];
            float i2 = iou * iou;
            al = __builtin_amdgcn_sqrtf(sg) * (i2 * i2 * i2);
        }
        cmax = fmaxf(cmax, al);
        unsigned long long msk = __ballot(valid && (al > 1e-9f));
        if (lane == 0) pc[m][wv1] = __popcll(msk);
    }
    cm[t] = cmax;
    __syncthreads();
    if (t < 128 && valid) maxm[(size_t)b * NN + n] = fmaxf(cm[t], cm[t + 128]);
    // 40 parallel depth-1 global atomics reserve list space
    if (t < MM) {
        int tot = pc[t][0] + pc[t][1];
        baseLoc[t] = (tot > 0) ? atomicAdd(&cnts[b * MM + t], tot) : 0;
    }
    __syncthreads();

    // pass B: recompute al (VALU is cheap here), scatter with LDS offsets
    #pragma unroll
    for (int j = 0; j < 20; j++) {
        int m = mb + j;
        float gx1 = gtb[m*4+0], gy1 = gtb[m*4+1], gx2 = gtb[m*4+2], gy2 = gtb[m*4+3];
        float a2 = (gx2 - gx1) * (gy2 - gy1);
        float iw = fmaxf(fminf(px2, gx2) - fmaxf(px1, gx1), 0.f);
        float ih = fmaxf(fminf(py2, gy2) - fmaxf(py1, gy1), 0.f);
        float inter = iw * ih;
        float iou = fmaxf(inter * __builtin_amdgcn_rcpf(a1 + a2 - inter + 1e-16f), 0.f);
        float al = 0.f;
        if (valid) {
            float sg = (float)sc[nloc * SLOTP + slotm[m]];
            float i2 = iou * iou;
            al = __builtin_amdgcn_sqrtf(sg) * (i2 * i2 * i2);
        }
        bool pos = valid && (al > 1e-9f);
        unsigned long long msk = __ballot(pos);
        if (pos) {
            int idx = baseLoc[m] + (wv1 ? pc[m][0] : 0)
                    + __popcll(msk & ((1ull << lane) - 1ull));
            if (idx < CAP)
                lists[((size_t)(b * MM + m)) * CAP + idx] =
                    ((unsigned long long)__float_as_uint(al) << 32) | (unsigned)n;
        }
    }

    // softplus block reduction -> one atomic
    #pragma unroll
    for (int off = 32; off > 0; off >>= 1) sp += __shfl_down(sp, off);
    if ((t & 63) == 0) redf[t >> 6] = sp;
    __syncthreads();
    if (t == 0) atomicAdd(accum, redf[0] + redf[1] + redf[2] + redf[3]);
}

// ---------- K_topk: top-10 of compacted positives, LDS-only passes ----------
__global__ __launch_bounds__(64) void k_topk(const unsigned long long* __restrict__ lists,
                                             const int*   __restrict__ cnts,
                                             const float* __restrict__ maxm,
                                             int* __restrict__ tgt) {
    __shared__ unsigned long long keys[CAP];
    __shared__ unsigned long long sel[TOPKK];
    const int bm = blockIdx.x, b = bm / MM, m = bm % MM, t = threadIdx.x;
    int cnt = min(cnts[bm], CAP);
    int kk = min(TOPKK, cnt);
    for (int i = t; i < cnt; i += 64) {
        unsigned long long L = lists[(size_t)bm * CAP + i];
        keys[i] = (L & 0xFFFFFFFF00000000ull) | (0xFFFFFFFFull - (L & 0xFFFFFFFFull));
    }
    __syncthreads();
    for (int p = 0; p < kk; p++) {
        unsigned long long best = 0ull;
        for (int i = t; i < cnt; i += 64) best = keys[i] > best ? keys[i] : best;
        #pragma unroll
        for (int off = 32; off > 0; off >>= 1) {
            unsigned long long o = __shfl_xor(best, off);
            best = o > best ? o : best;
        }
        for (int i = t; i < cnt; i += 64) if (keys[i] == best) keys[i] = 0ull;
        if (t == 0) sel[p] = best;
        __syncthreads();
    }
    if (t < kk) {
        unsigned long long bb = sel[t];
        float v = __uint_as_float((unsigned)(bb >> 32));
        int n = (int)(0xFFFFFFFFull - (bb & 0xFFFFFFFFull));
        if (v == maxm[(size_t)b * NN + n]) atomicMin(&tgt[(size_t)b * NN + n], m);
    }
}

// ---------- K_fg: fg accumulation + fused finalize (last block writes out) ----
__global__ __launch_bounds__(256) void k_fg(const int*   __restrict__ tgt,
                                            const int*   __restrict__ gl,
                                            const float* __restrict__ gb,
                                            const float* __restrict__ ps,
                                            const float* __restrict__ pbb,
                                            const float* __restrict__ maxm,
                                            float* __restrict__ accum,
                                            float* __restrict__ out) {
    int i = blockIdx.x * 256 + threadIdx.x;   // i in [0, B*N)
    int t = threadIdx.x;
    float vdot = 0.f, vbox = 0.f, vfg = 0.f;
    int tg = tgt[i];
    if (tg < MM) {
        int b = i / NN;
        int lab = gl[b * MM + tg];
        float x = ps[(size_t)i * NCC + lab];
        float mm = maxm[i];
        float4 p = *(const float4*)(pbb + (size_t)i * 4);
        const float* g = gb + ((size_t)b * MM + tg) * 4;
        float a1 = (p.z - p.x) * (p.w - p.y);
        float a2 = (g[2] - g[0]) * (g[3] - g[1]);
        float iw = fmaxf(fminf(p.z, g[2]) - fmaxf(p.x, g[0]), 0.f);
        float ih = fmaxf(fminf(p.w, g[3]) - fmaxf(p.y, g[1]), 0.f);
        float inter = iw * ih;
        float iou = inter / (a1 + a2 - inter + 1e-16f);
        vdot = x * mm; vbox = 1.0f - iou; vfg = 1.0f;
    }
    #pragma unroll
    for (int off = 32; off > 0; off >>= 1) {
        vdot += __shfl_down(vdot, off);
        vbox += __shfl_down(vbox, off);
        vfg  += __shfl_down(vfg,  off);
    }
    __shared__ float r[3][4];
    if ((t & 63) == 0) { int wv = t >> 6; r[0][wv] = vdot; r[1][wv] = vbox; r[2][wv] = vfg; }
    __syncthreads();
    if (t < 3) {
        float s = r[t][0] + r[t][1] + r[t][2] + r[t][3];
        if (s != 0.f) atomicAdd(&accum[1 + t], s);
    }
    __syncthreads();                 // block's atomics complete before signaling
    __threadfence();
    if (t == 0) {
        int old = atomicAdd((int*)&accum[7], 1);
        if (old == (int)gridDim.x - 1) {   // last block finalizes
            float S0  = atomicAdd(&accum[0], 0.f);
            float dot = atomicAdd(&accum[1], 0.f);
            float box = atomicAdd(&accum[2], 0.f);
            float fg  = atomicAdd(&accum[3], 0.f);
            float ts  = fmaxf(fg, 1.0f);
            float cls = (S0 - dot) / ts;
            float lb  = (fg > 0.f) ? box / fg : 0.f;
            out[0] = cls + 1.5f * lb;
        }
    }
}

// ---------- launch ----------
extern "C" void kernel_launch(void* const* d_in, const int* in_sizes, int n_in,
                              void* d_out, int out_size, void* d_ws, size_t ws_size,
                              hipStream_t stream) {
    const float* ps = (const float*)d_in[0];   // pred_scores (B,N,NC)
    const float* pd = (const float*)d_in[1];   // pred_dist   (B,N,64)
    const int*   gl = (const int*)  d_in[2];   // gt_labels   (B,M,1)
    const float* gb = (const float*)d_in[3];   // gt_bboxes   (B,M,4)
    const float* w  = (const float*)d_in[4];   // dfl_weight  (16)

    char* ws = (char*)d_ws;
    constexpr size_t HDR_BYTES  = 8192;                                     // accum+done+cnts
    constexpr size_t PBB_BYTES  = (size_t)BB * NN * 4 * sizeof(float);      // 4.30 MB
    constexpr size_t MAXM_BYTES = (size_t)BB * NN * sizeof(float);          // 1.08 MB
    constexpr size_t TGT_BYTES  = (size_t)BB * NN * sizeof(int);            // 1.08 MB

    float* accum = (float*)ws;                 // [0]=S0 [1]=dot [2]=box [3]=fg [7]=done
    int*   cnts  = (int*)(ws + 64);
    float* pbb   = (float*)(ws + HDR_BYTES);
    float* maxm  = (float*)(ws + HDR_BYTES + PBB_BYTES);
    int*   tgt   = (int*)  (ws + HDR_BYTES + PBB_BYTES + MAXM_BYTES);
    unsigned long long* lists =
        (unsigned long long*)(ws + HDR_BYTES + PBB_BYTES + MAXM_BYTES + TGT_BYTES);

    hipMemsetAsync(ws, 0, HDR_BYTES, stream);  // accum + done + cnts in one node

    dim3 g3((NN + 127) / 128, BB);
    k_main<<<g3, 256, 0, stream>>>(ps, pd, gl, gb, w, pbb, maxm, cnts, lists, accum, tgt);
    k_topk<<<BB * MM, 64, 0, stream>>>(lists, cnts, maxm, tgt);
    k_fg<<<BB * NN / 256, 256, 0, stream>>>(tgt, gl, gb, ps, pbb, maxm, accum, (float*)d_out);
}

// Round 6
// 258.416 us; speedup vs baseline: 1.2426x; 1.0708x over previous
//
#include <hip/hip_runtime.h>
#include <cstdint>
#include <cstddef>

#define BB 32
#define NN 8400
#define NCC 80
#define MM 40
#define RM 16
#define TOPKK 10
#define CAP 2048      // max positives per (b,m) global list
#define SEG 48        // LDS stage slots per m per block (worst-case ~54, overflow -> global path)
#define SLOTP 42      // fp16 slot stride; 21 words, gcd(21,32)=1 -> conflict-free gather

// ---------- helpers ----------
__device__ __forceinline__ void anchor_xy(int n, float& ax, float& ay) {
    int s, x, y;
    if (n < 6400)      { s = 8;  y = n / 80;            x = n - y * 80; }
    else if (n < 8000) { int i = n - 6400; s = 16; y = i / 40; x = i - y * 40; }
    else               { int i = n - 8000; s = 32; y = i / 20; x = i - y * 20; }
    ax = ((float)x + 0.5f) * (float)s;
    ay = ((float)y + 0.5f) * (float)s;
}

// ---------- K_main: DFL + sigmoid/softplus tile + align + LDS-staged push ----
// grid: (ceil(N/128), B), 256 threads. One-pass phase 2 (r5's two-pass recompute
// regressed 76->95us). No min-wave launch bound (r4: forcing 8/EU spilled,
// WRITE 5MB->177MB). Positive push staged in LDS: independent ~120cyc shared
// atomics instead of a 20-deep global atomic+shfl chain.
__global__ __launch_bounds__(256) void k_main(const float* __restrict__ ps,
                                              const float* __restrict__ pd,
                                              const int*   __restrict__ gl,
                                              const float* __restrict__ gb,
                                              const float* __restrict__ w,
                                              float* __restrict__ pbb,
                                              float* __restrict__ maxm,
                                              int*   __restrict__ cnts,
                                              unsigned long long* __restrict__ lists,
                                              float* __restrict__ accum,
                                              int*   __restrict__ tgt) {
    __shared__ _Float16 sc[128 * SLOTP];  // sigmoid per (nloc, slot), fp16: 10.75 KB
    __shared__ float4 box[128];           // ltrb then pred box: 2 KB
    __shared__ float  gtb[MM * 4];
    __shared__ int    glab[MM];
    __shared__ int    slotm[MM];
    __shared__ int    cmap[NCC];
    __shared__ unsigned long long stage[MM * SEG];   // 15.36 KB
    __shared__ int    scnt[MM];
    __shared__ int    baseLoc[MM];
    __shared__ float  cm[256];
    __shared__ float  redf[4];
    const int b  = blockIdx.y;
    const int n0 = blockIdx.x * 128;
    const int t  = threadIdx.x;
    const int bm0 = b * MM;

    // prefetch first 4 score float4s: overlaps HBM latency with phase-0 DFL VALU
    float4 pf[4];
    #pragma unroll
    for (int k = 0; k < 4; k++) {
        int f = t + k * 256;
        int row = f / 20, c4 = f - row * 20;
        int nc = min(n0 + row, NN - 1);
        pf[k] = *(const float4*)(ps + ((size_t)(b * NN + nc)) * NCC + c4 * 4);
    }

    // folded tgt init: this block owns [n0, n0+128)
    if (t < 128 && n0 + t < NN) tgt[(size_t)b * NN + n0 + t] = 0x7F7F7F7F;

    if (t < MM * 4)              gtb[t] = gb[b * MM * 4 + t];
    if (t >= 192 && t < 192+MM)  glab[t - 192] = gl[b * MM + (t - 192)];
    if (t >= 64 && t < 64+NCC)   cmap[t - 64] = 0x7FFFFFFF;
    if (t >= 144 && t < 144+MM)  scnt[t - 144] = 0;
    __syncthreads();
    if (t < MM) atomicMin(&cmap[glab[t]], t);   // parallel label dedup
    __syncthreads();
    if (t < MM) slotm[t] = cmap[glab[t]];       // slot = representative m, in [0,MM)

    // ---- phase 0: DFL softmax-dot for this block's 128 anchors (512 sides) ----
    #pragma unroll
    for (int h = 0; h < 2; h++) {
        int f = t + h * 256;                    // (anchor,side) flat in [0,512)
        int a = f >> 2, side = f & 3;
        int nc = min(n0 + a, NN - 1);
        const float* p = pd + (((size_t)(b * NN + nc)) * 4 + side) * RM;
        float x[RM];
        #pragma unroll
        for (int i = 0; i < 4; i++) {
            float4 v = *(const float4*)(p + i * 4);
            x[i*4+0] = v.x; x[i*4+1] = v.y; x[i*4+2] = v.z; x[i*4+3] = v.w;
        }
        float mx = x[0];
        #pragma unroll
        for (int i = 1; i < RM; i++) mx = fmaxf(mx, x[i]);
        float s = 0.f, d = 0.f;
        #pragma unroll
        for (int i = 0; i < RM; i++) {
            float e = __builtin_amdgcn_exp2f((x[i] - mx) * 1.44269504f);
            s += e; d += e * w[i];
        }
        ((float*)box)[f] = d * __builtin_amdgcn_rcpf(s);
    }
    __syncthreads();
    if (t < 128) {
        int n = n0 + t;
        float ax, ay; anchor_xy(min(n, NN - 1), ax, ay);
        float4 v = box[t];
        float4 pb = make_float4(ax - v.x, ay - v.y, ax + v.z, ay + v.w);
        box[t] = pb;
        if (n < NN) *(float4*)(pbb + (size_t)(b * NN + n) * 4) = pb;
    }

    // ---- phase 1: 128x80 score tile; pf[0..3] + fresh batch of 6 ----
    float4 vv[6];
    #pragma unroll
    for (int k = 0; k < 6; k++) {
        int f = t + (4 + k) * 256;
        int row = f / 20, c4 = f - row * 20;
        int nc = min(n0 + row, NN - 1);
        vv[k] = *(const float4*)(ps + ((size_t)(b * NN + nc)) * NCC + c4 * 4);
    }
    float sp = 0.f;
    #pragma unroll
    for (int k = 0; k < 10; k++) {
        int f = t + k * 256;
        int row = f / 20, c4 = f - row * 20;
        float vmask = (n0 + row < NN) ? 1.f : 0.f;
        float4 v = (k < 4) ? pf[k] : vv[k - 4];
        float xs[4] = {v.x, v.y, v.z, v.w};
        #pragma unroll
        for (int j = 0; j < 4; j++) {
            float x = xs[j];
            float e = __builtin_amdgcn_exp2f(-1.44269504f * fabsf(x));
            float r = __builtin_amdgcn_rcpf(1.0f + e);
            sp += vmask * (fmaxf(x, 0.f) + 0.69314718f * __builtin_amdgcn_logf(1.0f + e));
            int sl = cmap[c4 * 4 + j];
            if (sl < MM) sc[row * SLOTP + sl] = (_Float16)((x >= 0.f) ? r : e * r);
        }
    }
    __syncthreads();

    // ---- phase 2: align, one pass, LDS-staged positive push ----
    const int nloc = t & 127;
    const int n    = n0 + nloc;
    const int mb   = (t >> 7) * 20;
    const bool valid = (n < NN);
    float cmax = -INFINITY;
    float4 p4 = box[nloc];
    const float px1 = p4.x, py1 = p4.y, px2 = p4.z, py2 = p4.w;
    const float a1 = (px2 - px1) * (py2 - py1);
    #pragma unroll
    for (int j = 0; j < 20; j++) {
        int m = mb + j;
        float gx1 = gtb[m*4+0], gy1 = gtb[m*4+1], gx2 = gtb[m*4+2], gy2 = gtb[m*4+3];
        float a2 = (gx2 - gx1) * (gy2 - gy1);
        float iw = fmaxf(fminf(px2, gx2) - fmaxf(px1, gx1), 0.f);
        float ih = fmaxf(fminf(py2, gy2) - fmaxf(py1, gy1), 0.f);
        float inter = iw * ih;
        float iou = fmaxf(inter * __builtin_amdgcn_rcpf(a1 + a2 - inter + 1e-16f), 0.f);
        float al = 0.f;
        if (valid) {
            float sg = (float)sc[nloc * SLOTP + slotm[m]];
            float i2 = iou * iou;
            al = __builtin_amdgcn_sqrtf(sg) * (i2 * i2 * i2);
        }
        cmax = fmaxf(cmax, al);
        if (al > 1e-9f) {   // implies valid
            unsigned long long key =
                ((unsigned long long)__float_as_uint(al) << 32) | (unsigned)n;
            int li = atomicAdd(&scnt[m], 1);
            if (li < SEG) stage[m * SEG + li] = key;
            else {          // rare overflow: direct global push
                int gi = atomicAdd(&cnts[bm0 + m], 1);
                if (gi < CAP) lists[((size_t)(bm0 + m)) * CAP + gi] = key;
            }
        }
    }
    cm[t] = cmax;
    __syncthreads();
    if (t < 128 && valid) maxm[(size_t)b * NN + n] = fmaxf(cm[t], cm[t + 128]);
    // batched reservation: 40 parallel depth-1 global atomics
    if (t < MM) {
        int ns = min(scnt[t], SEG);
        baseLoc[t] = (ns > 0) ? atomicAdd(&cnts[bm0 + t], ns) : 0;
    }
    __syncthreads();
    // cooperative coalesced copy-out of staged positives
    for (int f = t; f < MM * SEG; f += 256) {
        int m = f / SEG, i = f - m * SEG;
        if (i < min(scnt[m], SEG)) {
            int gi = baseLoc[m] + i;
            if (gi < CAP) lists[((size_t)(bm0 + m)) * CAP + gi] = stage[f];
        }
    }

    // softplus block reduction -> one atomic
    #pragma unroll
    for (int off = 32; off > 0; off >>= 1) sp += __shfl_down(sp, off);
    if ((t & 63) == 0) redf[t >> 6] = sp;
    __syncthreads();
    if (t == 0) atomicAdd(accum, redf[0] + redf[1] + redf[2] + redf[3]);
}

// ---------- K_topk: top-10 of compacted positives, LDS-only passes ----------
__global__ __launch_bounds__(64) void k_topk(const unsigned long long* __restrict__ lists,
                                             const int*   __restrict__ cnts,
                                             const float* __restrict__ maxm,
                                             int* __restrict__ tgt) {
    __shared__ unsigned long long keys[CAP];
    __shared__ unsigned long long sel[TOPKK];
    const int bm = blockIdx.x, b = bm / MM, m = bm % MM, t = threadIdx.x;
    int cnt = min(cnts[bm], CAP);
    int kk = min(TOPKK, cnt);
    for (int i = t; i < cnt; i += 64) {
        unsigned long long L = lists[(size_t)bm * CAP + i];
        keys[i] = (L & 0xFFFFFFFF00000000ull) | (0xFFFFFFFFull - (L & 0xFFFFFFFFull));
    }
    __syncthreads();
    for (int p = 0; p < kk; p++) {
        unsigned long long best = 0ull;
        for (int i = t; i < cnt; i += 64) best = keys[i] > best ? keys[i] : best;
        #pragma unroll
        for (int off = 32; off > 0; off >>= 1) {
            unsigned long long o = __shfl_xor(best, off);
            best = o > best ? o : best;
        }
        for (int i = t; i < cnt; i += 64) if (keys[i] == best) keys[i] = 0ull;
        if (t == 0) sel[p] = best;
        __syncthreads();
    }
    if (t < kk) {
        unsigned long long bb = sel[t];
        float v = __uint_as_float((unsigned)(bb >> 32));
        int n = (int)(0xFFFFFFFFull - (bb & 0xFFFFFFFFull));
        if (v == maxm[(size_t)b * NN + n]) atomicMin(&tgt[(size_t)b * NN + n], m);
    }
}

// ---------- K_fg: fg accumulation + fused finalize (last block writes out) ----
__global__ __launch_bounds__(256) void k_fg(const int*   __restrict__ tgt,
                                            const int*   __restrict__ gl,
                                            const float* __restrict__ gb,
                                            const float* __restrict__ ps,
                                            const float* __restrict__ pbb,
                                            const float* __restrict__ maxm,
                                            float* __restrict__ accum,
                                            float* __restrict__ out) {
    int i = blockIdx.x * 256 + threadIdx.x;   // i in [0, B*N)
    int t = threadIdx.x;
    float vdot = 0.f, vbox = 0.f, vfg = 0.f;
    int tg = tgt[i];
    if (tg < MM) {
        int b = i / NN;
        int lab = gl[b * MM + tg];
        float x = ps[(size_t)i * NCC + lab];
        float mm = maxm[i];
        float4 p = *(const float4*)(pbb + (size_t)i * 4);
        const float* g = gb + ((size_t)b * MM + tg) * 4;
        float a1 = (p.z - p.x) * (p.w - p.y);
        float a2 = (g[2] - g[0]) * (g[3] - g[1]);
        float iw = fmaxf(fminf(p.z, g[2]) - fmaxf(p.x, g[0]), 0.f);
        float ih = fmaxf(fminf(p.w, g[3]) - fmaxf(p.y, g[1]), 0.f);
        float inter = iw * ih;
        float iou = inter / (a1 + a2 - inter + 1e-16f);
        vdot = x * mm; vbox = 1.0f - iou; vfg = 1.0f;
    }
    #pragma unroll
    for (int off = 32; off > 0; off >>= 1) {
        vdot += __shfl_down(vdot, off);
        vbox += __shfl_down(vbox, off);
        vfg  += __shfl_down(vfg,  off);
    }
    __shared__ float r[3][4];
    if ((t & 63) == 0) { int wv = t >> 6; r[0][wv] = vdot; r[1][wv] = vbox; r[2][wv] = vfg; }
    __syncthreads();
    if (t < 3) {
        float s = r[t][0] + r[t][1] + r[t][2] + r[t][3];
        if (s != 0.f) atomicAdd(&accum[1 + t], s);
    }
    __syncthreads();                 // block's atomics complete before signaling
    __threadfence();
    if (t == 0) {
        int old = atomicAdd((int*)&accum[7], 1);
        if (old == (int)gridDim.x - 1) {   // last block finalizes
            float S0  = atomicAdd(&accum[0], 0.f);
            float dot = atomicAdd(&accum[1], 0.f);
            float box = atomicAdd(&accum[2], 0.f);
            float fg  = atomicAdd(&accum[3], 0.f);
            float ts  = fmaxf(fg, 1.0f);
            float cls = (S0 - dot) / ts;
            float lb  = (fg > 0.f) ? box / fg : 0.f;
            out[0] = cls + 1.5f * lb;
        }
    }
}

// ---------- launch ----------
extern "C" void kernel_launch(void* const* d_in, const int* in_sizes, int n_in,
                              void* d_out, int out_size, void* d_ws, size_t ws_size,
                              hipStream_t stream) {
    const float* ps = (const float*)d_in[0];   // pred_scores (B,N,NC)
    const float* pd = (const float*)d_in[1];   // pred_dist   (B,N,64)
    const int*   gl = (const int*)  d_in[2];   // gt_labels   (B,M,1)
    const float* gb = (const float*)d_in[3];   // gt_bboxes   (B,M,4)
    const float* w  = (const float*)d_in[4];   // dfl_weight  (16)

    char* ws = (char*)d_ws;
    constexpr size_t HDR_BYTES  = 8192;                                     // accum+done+cnts
    constexpr size_t PBB_BYTES  = (size_t)BB * NN * 4 * sizeof(float);      // 4.30 MB
    constexpr size_t MAXM_BYTES = (size_t)BB * NN * sizeof(float);          // 1.08 MB
    constexpr size_t TGT_BYTES  = (size_t)BB * NN * sizeof(int);            // 1.08 MB

    float* accum = (float*)ws;                 // [0]=S0 [1]=dot [2]=box [3]=fg [7]=done
    int*   cnts  = (int*)(ws + 64);
    float* pbb   = (float*)(ws + HDR_BYTES);
    float* maxm  = (float*)(ws + HDR_BYTES + PBB_BYTES);
    int*   tgt   = (int*)  (ws + HDR_BYTES + PBB_BYTES + MAXM_BYTES);
    unsigned long long* lists =
        (unsigned long long*)(ws + HDR_BYTES + PBB_BYTES + MAXM_BYTES + TGT_BYTES);

    hipMemsetAsync(ws, 0, HDR_BYTES, stream);  // accum + done + cnts in one node

    dim3 g3((NN + 127) / 128, BB);
    k_main<<<g3, 256, 0, stream>>>(ps, pd, gl, gb, w, pbb, maxm, cnts, lists, accum, tgt);
    k_topk<<<BB * MM, 64, 0, stream>>>(lists, cnts, maxm, tgt);
    k_fg<<<BB * NN / 256, 256, 0, stream>>>(tgt, gl, gb, ps, pbb, maxm, accum, (float*)d_out);
}